// Round 3
// baseline (86.882 us; speedup 1.0000x reference)
//
#include <hip/hip_runtime.h>

#define NSHAPES 32
#define BLOCK 256
#define SLOTS 4   // half2 slots per thread; 2 points each => 8 points/thread

// Packed-fp16 multi-rect SDF via clang-native _Float16 vectors (ROCm 7.2's
// hip_fp16.h lacks __hmax2/__hmin2/__habs2 overloads — avoid it entirely).
// Each lane processes 2 points per VOP3P instruction. Per shape per slot:
//   rx = C*qx + (NS*qy + NTX)      2x v_pk_fma_f16
//   ry = S*qx + (C*qy + NTY)       2x v_pk_fma_f16
//   dx = |rx| - RDX                v_and_b32 + v_pk_add_f16
//   dy = |ry| - RDY                2
//   m  = max(dx,dy)                1
//   mx = max(dx,0); my = max(dy,0) 2
//   sq = mx*mx + my*my             2 (pk_mul + pk_fma)
//   minSq=min(,sq); minIn=min(,m)  2
// = 15 packed insts / 2 points = 7.5 insts/shape-point (fp32 version: 13).
// Final per point (fp32): minIn<0 ? minIn : sqrt(minSq).

typedef _Float16 h2 __attribute__((ext_vector_type(2)));

union HU32 { unsigned int u; h2 h; };
__device__ __forceinline__ h2 u2h(unsigned int x) { HU32 t; t.u = x; return t.h; }

__global__ __launch_bounds__(BLOCK) void multi_rect_sdf_fp16(
    const float4* __restrict__ query4,   // n_f4 float4s = 2 points each
    const float*  __restrict__ trans,    // (32,2)
    const float*  __restrict__ rads,     // (32,2)
    const float*  __restrict__ angles,   // (32,)
    float2*       __restrict__ out2,     // n_f4 float2s
    int n_f4)
{
    __shared__ uint4 PA[NSHAPES];  // {C2, S2, NS2, NTX2} as broadcast half2 bits
    __shared__ uint4 PB[NSHAPES];  // {NTY2, RDX2, RDY2, pad}

    const int t = threadIdx.x;
    if (t < NSHAPES) {
        float a  = angles[t];
        float c  = cosf(a), s = sinf(a);
        float tx = trans[2 * t], ty = trans[2 * t + 1];
        float rx = rads[2 * t],  ry = rads[2 * t + 1];
        auto pk = [](float v) -> unsigned int {
            union { _Float16 h; unsigned short u; } w;
            w.h = (_Float16)v;
            return ((unsigned int)w.u << 16) | w.u;   // broadcast both halves
        };
        PA[t] = make_uint4(pk(c), pk(s), pk(-s), pk(-tx));
        PB[t] = make_uint4(pk(-ty), pk(rx), pk(ry), 0u);
    }
    __syncthreads();

    const int f4_per_block = BLOCK * SLOTS;   // 1024
    const int base = blockIdx.x * f4_per_block + t;

    // Coalesced float4 loads (2 fp32 points) -> packed {x0,x1},{y0,y1}
    h2 qx2[SLOTS], qy2[SLOTS];
    #pragma unroll
    for (int j = 0; j < SLOTS; ++j) {
        int idx = base + j * BLOCK;
        float4 q = (idx < n_f4) ? query4[idx] : make_float4(0.f, 0.f, 0.f, 0.f);
        qx2[j] = (h2){ (_Float16)q.x, (_Float16)q.z };
        qy2[j] = (h2){ (_Float16)q.y, (_Float16)q.w };
    }

    const h2 z2 = (h2){ (_Float16)0.0f, (_Float16)0.0f };
    h2 minSq[SLOTS], minIn[SLOTS];
    #pragma unroll
    for (int j = 0; j < SLOTS; ++j) {
        minSq[j] = (h2){ (_Float16)60000.0f, (_Float16)60000.0f };
        minIn[j] = z2;
    }

    #pragma unroll 4
    for (int k = 0; k < NSHAPES; ++k) {
        uint4 pa = PA[k];   // broadcast ds_read_b128
        uint4 pb = PB[k];
        h2 C2   = u2h(pa.x), S2   = u2h(pa.y);
        h2 NS2  = u2h(pa.z), NTX2 = u2h(pa.w);
        h2 NTY2 = u2h(pb.x), RDX2 = u2h(pb.y), RDY2 = u2h(pb.z);
        #pragma unroll
        for (int j = 0; j < SLOTS; ++j) {
            h2 rx = __builtin_elementwise_fma(C2, qx2[j],
                        __builtin_elementwise_fma(NS2, qy2[j], NTX2));
            h2 ry = __builtin_elementwise_fma(S2, qx2[j],
                        __builtin_elementwise_fma(C2, qy2[j], NTY2));
            h2 dx = __builtin_elementwise_abs(rx) - RDX2;
            h2 dy = __builtin_elementwise_abs(ry) - RDY2;
            h2 m  = __builtin_elementwise_max(dx, dy);
            h2 mx = __builtin_elementwise_max(dx, z2);
            h2 my = __builtin_elementwise_max(dy, z2);
            h2 sq = __builtin_elementwise_fma(mx, mx, my * my);
            minSq[j] = __builtin_elementwise_min(minSq[j], sq);
            minIn[j] = __builtin_elementwise_min(minIn[j], m);
        }
    }

    #pragma unroll
    for (int j = 0; j < SLOTS; ++j) {
        int idx = base + j * BLOCK;
        if (idx < n_f4) {
            float in0 = (float)minIn[j].x, in1 = (float)minIn[j].y;
            float sq0 = (float)minSq[j].x, sq1 = (float)minSq[j].y;
            float r0 = (in0 < 0.0f) ? in0 : sqrtf(sq0);
            float r1 = (in1 < 0.0f) ? in1 : sqrtf(sq1);
            out2[idx] = make_float2(r0, r1);
        }
    }
}

extern "C" void kernel_launch(void* const* d_in, const int* in_sizes, int n_in,
                              void* d_out, int out_size, void* d_ws, size_t ws_size,
                              hipStream_t stream) {
    const float* query  = (const float*)d_in[0];
    const float* trans  = (const float*)d_in[1];
    const float* rads   = (const float*)d_in[2];
    const float* angles = (const float*)d_in[3];
    float* out = (float*)d_out;

    const int n_points = in_sizes[0] / 2;   // (N,2) -> N
    const int n_f4 = n_points / 2;          // 2 points per float4
    const int f4_per_block = BLOCK * SLOTS;
    const int grid = (n_f4 + f4_per_block - 1) / f4_per_block;

    multi_rect_sdf_fp16<<<grid, BLOCK, 0, stream>>>(
        (const float4*)query, trans, rads, angles, (float2*)out, n_f4);
}